// Round 3
// baseline (1508.201 us; speedup 1.0000x reference)
//
#include <hip/hip_runtime.h>

#define D_  2048
#define H_  16
#define HD_ 128
#define FF_ 8192
#define T_  2048
#define B_  2
#define BT_ (B_*T_)
#define NP_ (B_*H_)        // 32 (b,h) pairs
#define CH_ 8              // pairs per attention chunk
#define NCH_ (NP_/CH_)     // 4 chunks

typedef __attribute__((ext_vector_type(8))) _Float16 half8;
typedef __attribute__((ext_vector_type(4))) float   floatx4;

// ---------------- weight convert + transpose: W[K][N] f32 -> Wt[N][K] f16 ----
__global__ void wconv_kernel(const float* __restrict__ W, _Float16* __restrict__ Wt,
                             int K, int N) {
  __shared__ float tile[32][33];
  int n0 = blockIdx.x * 32, k0 = blockIdx.y * 32;
  int tx = threadIdx.x, ty = threadIdx.y;   // 32 x 8
#pragma unroll
  for (int r = 0; r < 32; r += 8)
    tile[ty + r][tx] = W[(size_t)(k0 + ty + r) * N + n0 + tx];
  __syncthreads();
#pragma unroll
  for (int r = 0; r < 32; r += 8)
    Wt[(size_t)(n0 + ty + r) * K + k0 + tx] = (_Float16)tile[tx][ty + r];
}

// ---------------- rmsnorm: fp32 row -> fp16 row --------------------------------
__global__ void rmsnorm_kernel(const float* __restrict__ x, const float* __restrict__ g,
                               _Float16* __restrict__ out) {
  int row = blockIdx.x, tid = threadIdx.x;
  const float4* xr = (const float4*)(x + (size_t)row * D_);
  float4 v1 = xr[tid], v2 = xr[tid + 256];
  float ss = v1.x*v1.x + v1.y*v1.y + v1.z*v1.z + v1.w*v1.w
           + v2.x*v2.x + v2.y*v2.y + v2.z*v2.z + v2.w*v2.w;
  __shared__ float red[256];
  red[tid] = ss; __syncthreads();
  for (int s = 128; s > 0; s >>= 1) { if (tid < s) red[tid] += red[tid + s]; __syncthreads(); }
  float rs = rsqrtf(red[0] * (1.0f / D_) + 1e-6f);
  float4 ga = ((const float4*)g)[tid], gb = ((const float4*)g)[tid + 256];
  _Float16* orow = out + (size_t)row * D_;
  _Float16 t[4] __attribute__((aligned(8)));
  t[0] = (_Float16)(v1.x * rs * ga.x);
  t[1] = (_Float16)(v1.y * rs * ga.y);
  t[2] = (_Float16)(v1.z * rs * ga.z);
  t[3] = (_Float16)(v1.w * rs * ga.w);
  *(uint2*)(orow + tid * 4) = *(const uint2*)t;
  t[0] = (_Float16)(v2.x * rs * gb.x);
  t[1] = (_Float16)(v2.y * rs * gb.y);
  t[2] = (_Float16)(v2.z * rs * gb.z);
  t[3] = (_Float16)(v2.w * rs * gb.w);
  *(uint2*)(orow + (tid + 256) * 4) = *(const uint2*)t;
}

// ---------------- generic MFMA GEMM, C = A @ Bt^T ------------------------------
// A: M x K (lda), Bt: N x K (ldb), C: M x N (ldc).  128x128 tile, 4 waves.
// CMODE: 0 none, 1 causal tile-skip (scores), 2 causal K-limit (PV).
// ADDRES: 1 -> C fp32 = acc + Res;  0 -> C fp16 = acc.
// Batch: p = pair0 + blockIdx.z; b=p>>4, h=p&15.
//   A offset: (LOCALS&1) ? blockIdx.z*sAd : b*sAd + h*sAm
//   B offset:                               b*sBd + h*sBm
//   C offset: (LOCALS&2) ? blockIdx.z*sCd : b*sCd + h*sCm
template<int CMODE, int ADDRES, int LOCALS>
__global__ __launch_bounds__(256, 2) void gemm_bt(
    const _Float16* __restrict__ A, const _Float16* __restrict__ Bt,
    void* __restrict__ Cv, const float* __restrict__ Res,
    int M, int N, int K, int lda, int ldb, int ldc, int pair0,
    long long sAd, long long sAm, long long sBd, long long sBm,
    long long sCd, long long sCm)
{
  int zl = blockIdx.z;
  int p = pair0 + zl;
  long long aoff = (LOCALS & 1) ? (long long)zl * sAd
                                : (long long)(p >> 4) * sAd + (long long)(p & 15) * sAm;
  long long boff = (long long)(p >> 4) * sBd + (long long)(p & 15) * sBm;
  long long coff = (LOCALS & 2) ? (long long)zl * sCd
                                : (long long)(p >> 4) * sCd + (long long)(p & 15) * sCm;
  const _Float16* Ab = A + (size_t)aoff;
  const _Float16* Bb = Bt + (size_t)boff;
  int m0 = blockIdx.y * 128, n0 = blockIdx.x * 128;
  if (CMODE == 1 && n0 > m0 + 127) return;
  int kmax = K;
  if (CMODE == 2) kmax = min(K, m0 + 128);

  __shared__ __align__(16) _Float16 As[128 * 40];
  __shared__ __align__(16) _Float16 Bs[128 * 40];

  int tid = threadIdx.x;
  int lane = tid & 63;
  int wm = ((tid >> 7) & 1) * 64;   // wave row
  int wn = ((tid >> 6) & 1) * 64;   // wave col
  int l15 = lane & 15, q4 = lane >> 4;

  floatx4 acc[4][4];
#pragma unroll
  for (int i = 0; i < 4; i++)
#pragma unroll
    for (int j = 0; j < 4; j++)
#pragma unroll
      for (int r = 0; r < 4; r++) acc[i][j][r] = 0.0f;

  for (int k0 = 0; k0 < kmax; k0 += 32) {
#pragma unroll
    for (int c = 0; c < 2; c++) {
      int idx = tid + c * 256;              // 0..511
      int row = idx >> 2, gc = (idx & 3) << 3;
      *(uint4*)(&As[row * 40 + gc]) = *(const uint4*)(Ab + (size_t)(m0 + row) * lda + k0 + gc);
      *(uint4*)(&Bs[row * 40 + gc]) = *(const uint4*)(Bb + (size_t)(n0 + row) * ldb + k0 + gc);
    }
    __syncthreads();
    half8 af[4], bfr[4];
#pragma unroll
    for (int i = 0; i < 4; i++)
      af[i] = *(const half8*)(&As[(wm + i * 16 + l15) * 40 + q4 * 8]);
#pragma unroll
    for (int j = 0; j < 4; j++)
      bfr[j] = *(const half8*)(&Bs[(wn + j * 16 + l15) * 40 + q4 * 8]);
#pragma unroll
    for (int i = 0; i < 4; i++)
#pragma unroll
      for (int j = 0; j < 4; j++)
        acc[i][j] = __builtin_amdgcn_mfma_f32_16x16x32_f16(af[i], bfr[j], acc[i][j], 0, 0, 0);
    __syncthreads();
  }

#pragma unroll
  for (int i = 0; i < 4; i++) {
#pragma unroll
    for (int j = 0; j < 4; j++) {
#pragma unroll
      for (int r = 0; r < 4; r++) {
        int row = m0 + wm + i * 16 + q4 * 4 + r;
        int col = n0 + wn + j * 16 + l15;
        size_t o = (size_t)(coff + (long long)row * ldc + col);
        if (ADDRES) ((float*)Cv)[o] = acc[i][j][r] + Res[o];
        else        ((_Float16*)Cv)[o] = (_Float16)acc[i][j][r];
      }
    }
  }
}

// ---------------- RoPE on q and k (in place) ------------------------------------
__global__ void rope_kernel(_Float16* __restrict__ q, _Float16* __restrict__ k,
                            const void* __restrict__ pos) {
  int gid = blockIdx.x * 256 + threadIdx.x;   // BT_*H_*64 threads
  int d = gid & 63;
  int h = (gid >> 6) & 15;
  int bt = gid >> 10;
  const int* pi = (const int*)pos;
  // detect int64 vs int32 layout of position_ids (values are arange 0..BT-1)
  long long p = (pi[1] == 0 && pi[2] == 1) ? ((const long long*)pos)[bt]
                                           : (long long)pi[bt];
  float inv = exp2f((float)d * -0.2076205059304601f);  // 10000^(-d/64)
  float ang = (float)p * inv;
  float s, c;
  // accurate sincos: full range reduction (angles reach ~4095 rad), and note
  // the signature is (x, &sin, &cos) — previous round had them swapped.
  sincosf(ang, &s, &c);
  size_t base = (size_t)bt * D_ + (size_t)h * HD_ + d;
  float x1 = (float)q[base], x2 = (float)q[base + 64];
  q[base]      = (_Float16)(x1 * c - x2 * s);
  q[base + 64] = (_Float16)(x2 * c + x1 * s);
  x1 = (float)k[base]; x2 = (float)k[base + 64];
  k[base]      = (_Float16)(x1 * c - x2 * s);
  k[base + 64] = (_Float16)(x2 * c + x1 * s);
}

// ---------------- v[b][t][h*HD+d] -> vt[(b*H+h)][d][t] --------------------------
__global__ void vtrans_kernel(const _Float16* __restrict__ v, _Float16* __restrict__ vt) {
  __shared__ _Float16 tile[32][33];
  int t0 = blockIdx.x * 32, d0 = blockIdx.y * 32, bh = blockIdx.z;
  int b = bh >> 4, h = bh & 15;
  int tx = threadIdx.x, ty = threadIdx.y;   // 32 x 8
  const _Float16* vb = v + (size_t)b * T_ * D_ + (size_t)h * HD_;
#pragma unroll
  for (int r = 0; r < 32; r += 8)
    tile[ty + r][tx] = vb[(size_t)(t0 + ty + r) * D_ + d0 + tx];
  __syncthreads();
  _Float16* vo = vt + ((size_t)bh * HD_ + d0) * T_ + t0;
#pragma unroll
  for (int r = 0; r < 32; r += 8)
    vo[(size_t)(ty + r) * T_ + tx] = tile[tx][ty + r];
}

// ---------------- causal softmax over one row of scores (in place) --------------
// probs holds CH_ pairs x T_ rows of T_; query index = rowid & (T_-1)
__global__ void softmax_kernel(_Float16* __restrict__ probs) {
  long long rowid = blockIdx.x;
  int i = (int)(rowid & (T_ - 1));
  _Float16* row = probs + (size_t)rowid * T_;
  int tid = threadIdx.x;
  int j0 = tid * 8;
  uint4 raw = *(const uint4*)(row + j0);
  const _Float16* ph = (const _Float16*)&raw;
  const float scale = 0.08838834764831845f;     // 1/sqrt(128)
  float vals[8];
  float mx = -1e30f;
#pragma unroll
  for (int l = 0; l < 8; l++) {
    float v = (j0 + l <= i) ? (float)ph[l] * scale : -1e30f;
    vals[l] = v; mx = fmaxf(mx, v);
  }
  __shared__ float red[256];
  red[tid] = mx; __syncthreads();
  for (int s = 128; s > 0; s >>= 1) { if (tid < s) red[tid] = fmaxf(red[tid], red[tid + s]); __syncthreads(); }
  float M = red[0]; __syncthreads();
  float se = 0.f;
#pragma unroll
  for (int l = 0; l < 8; l++) { float e = __expf(vals[l] - M); vals[l] = e; se += e; }
  red[tid] = se; __syncthreads();
  for (int s = 128; s > 0; s >>= 1) { if (tid < s) red[tid] += red[tid + s]; __syncthreads(); }
  float inv = 1.0f / red[0];
  _Float16 t[8] __attribute__((aligned(16)));
#pragma unroll
  for (int l = 0; l < 8; l++) t[l] = (j0 + l <= i) ? (_Float16)(vals[l] * inv) : (_Float16)0.f;
  *(uint4*)(row + j0) = *(const uint4*)t;
}

// ---------------- hu = silu(gate) * up  (written over gate) ---------------------
__global__ void silumul_kernel(_Float16* __restrict__ gate, const _Float16* __restrict__ up) {
  size_t idx = ((size_t)blockIdx.x * 256 + threadIdx.x) * 8;
  uint4 gr = *(const uint4*)(gate + idx);
  uint4 ur = *(const uint4*)(up + idx);
  const _Float16* gh = (const _Float16*)&gr;
  const _Float16* uh = (const _Float16*)&ur;
  _Float16 t[8] __attribute__((aligned(16)));
#pragma unroll
  for (int l = 0; l < 8; l++) {
    float x = (float)gh[l];
    float s = x / (1.0f + __expf(-x));
    t[l] = (_Float16)(s * (float)uh[l]);
  }
  *(uint4*)(gate + idx) = *(const uint4*)t;
}

// ================================================================================
extern "C" void kernel_launch(void* const* d_in, const int* in_sizes, int n_in,
                              void* d_out, int out_size, void* d_ws, size_t ws_size,
                              hipStream_t stream) {
  (void)in_sizes; (void)n_in; (void)out_size; (void)ws_size;
  const float* x   = (const float*)d_in[0];
  const void*  pos = d_in[1];
  const float* Wq  = (const float*)d_in[2];
  const float* Wk  = (const float*)d_in[3];
  const float* Wv  = (const float*)d_in[4];
  const float* Wo  = (const float*)d_in[5];
  const float* Wg  = (const float*)d_in[6];
  const float* Wu  = (const float*)d_in[7];
  const float* Wd  = (const float*)d_in[8];
  const float* g1  = (const float*)d_in[9];
  const float* g2  = (const float*)d_in[10];
  float* out = (float*)d_out;

  // ---- workspace layout (total ~208 MB), lifetime-overlaid ----
  char* p = (char*)d_ws;
  auto carve = [&](size_t bytes) { char* r = p; p += (bytes + 255) & ~(size_t)255; return r; };
  _Float16* probs = (_Float16*)carve((size_t)CH_ * T_ * T_ * 2);   // 64 MB; later: gate
  _Float16* wslot = (_Float16*)carve((size_t)D_ * FF_ * 2);        // 32 MB rotating weight slot
  _Float16* qb    = (_Float16*)carve((size_t)BT_ * D_ * 2);        // 16 MB; later: hb
  _Float16* xn    = (_Float16*)carve((size_t)BT_ * D_ * 2);        // 16 MB; later: ob, then part of up
  _Float16* kb    = (_Float16*)carve((size_t)BT_ * D_ * 2);        // 16 MB; later part of up
  _Float16* vb    = (_Float16*)carve((size_t)BT_ * D_ * 2);        // 16 MB; later part of up
  _Float16* vt    = (_Float16*)carve((size_t)BT_ * D_ * 2);        // 16 MB; later part of up
  float*    x1    = (float*)   carve((size_t)BT_ * D_ * 4);        // 32 MB
  _Float16* gate  = probs;            // 64 MB, probs dead by then
  _Float16* up    = xn;               // 64 MB spans xn|kb|vb|vt, all dead by then
  _Float16* ob    = xn;               // reuse xn after QKV
  _Float16* hb    = qb;               // reuse qb after attention

  dim3 b328(32, 8);

  // xn = rmsnorm(x, g1)
  rmsnorm_kernel<<<BT_, 256, 0, stream>>>(x, g1, xn);

  // q, k, v projections (JIT weight conversion into rotating slot)
  wconv_kernel<<<dim3(D_ / 32, D_ / 32), b328, 0, stream>>>(Wq, wslot, D_, D_);
  gemm_bt<0, 0, 0><<<dim3(D_ / 128, BT_ / 128, 1), 256, 0, stream>>>(
      xn, wslot, qb, nullptr, BT_, D_, D_, D_, D_, D_, 0, 0, 0, 0, 0, 0, 0);
  wconv_kernel<<<dim3(D_ / 32, D_ / 32), b328, 0, stream>>>(Wk, wslot, D_, D_);
  gemm_bt<0, 0, 0><<<dim3(D_ / 128, BT_ / 128, 1), 256, 0, stream>>>(
      xn, wslot, kb, nullptr, BT_, D_, D_, D_, D_, D_, 0, 0, 0, 0, 0, 0, 0);
  wconv_kernel<<<dim3(D_ / 32, D_ / 32), b328, 0, stream>>>(Wv, wslot, D_, D_);
  gemm_bt<0, 0, 0><<<dim3(D_ / 128, BT_ / 128, 1), 256, 0, stream>>>(
      xn, wslot, vb, nullptr, BT_, D_, D_, D_, D_, D_, 0, 0, 0, 0, 0, 0, 0);

  // rope(q, k)
  rope_kernel<<<(BT_ * H_ * 64) / 256, 256, 0, stream>>>(qb, kb, pos);

  // v transpose per head: vt[(b*H+h)][d][t]
  vtrans_kernel<<<dim3(T_ / 32, HD_ / 32, B_ * H_), b328, 0, stream>>>(vb, vt);

  // attention in chunks of CH_ (b,h) pairs
  for (int c = 0; c < NCH_; c++) {
    // scores = q @ k^T  (C chunk-local)
    gemm_bt<1, 0, 2><<<dim3(T_ / 128, T_ / 128, CH_), 256, 0, stream>>>(
        qb, kb, probs, nullptr, T_, T_, HD_, D_, D_, T_, c * CH_,
        (long long)T_ * D_, HD_, (long long)T_ * D_, HD_,
        (long long)T_ * T_, 0);
    // causal softmax rows of this chunk
    softmax_kernel<<<CH_ * T_, 256, 0, stream>>>(probs);
    // o = probs @ v  (A chunk-local)
    gemm_bt<2, 0, 1><<<dim3(1, T_ / 128, CH_), 256, 0, stream>>>(
        probs, vt, ob, nullptr, T_, HD_, T_, T_, T_, D_, c * CH_,
        (long long)T_ * T_, 0,
        16LL * HD_ * T_, (long long)HD_ * T_,
        (long long)T_ * D_, HD_);
  }

  // x1 = x + o @ Wo
  wconv_kernel<<<dim3(D_ / 32, D_ / 32), b328, 0, stream>>>(Wo, wslot, D_, D_);
  gemm_bt<0, 1, 0><<<dim3(D_ / 128, BT_ / 128, 1), 256, 0, stream>>>(
      ob, wslot, x1, x, BT_, D_, D_, D_, D_, D_, 0, 0, 0, 0, 0, 0, 0);

  // h = rmsnorm(x1, g2)
  rmsnorm_kernel<<<BT_, 256, 0, stream>>>(x1, g2, hb);

  // gate = h @ Wg   (gate overlays probs region — probs dead)
  wconv_kernel<<<dim3(FF_ / 32, D_ / 32), b328, 0, stream>>>(Wg, wslot, D_, FF_);
  gemm_bt<0, 0, 0><<<dim3(FF_ / 128, BT_ / 128, 1), 256, 0, stream>>>(
      hb, wslot, gate, nullptr, BT_, FF_, D_, D_, D_, FF_, 0, 0, 0, 0, 0, 0, 0);
  // up = h @ Wu     (up overlays xn|kb|vb|vt — all dead)
  wconv_kernel<<<dim3(FF_ / 32, D_ / 32), b328, 0, stream>>>(Wu, wslot, D_, FF_);
  gemm_bt<0, 0, 0><<<dim3(FF_ / 128, BT_ / 128, 1), 256, 0, stream>>>(
      hb, wslot, up, nullptr, BT_, FF_, D_, D_, D_, FF_, 0, 0, 0, 0, 0, 0, 0);

  // hu = silu(gate) * up  (in gate)
  silumul_kernel<<<(BT_ * FF_ / 8) / 256, 256, 0, stream>>>(gate, up);

  // out = x1 + hu @ Wd
  wconv_kernel<<<dim3(D_ / 32, FF_ / 32), b328, 0, stream>>>(Wd, wslot, FF_, D_);
  gemm_bt<0, 1, 0><<<dim3(D_ / 128, BT_ / 128, 1), 256, 0, stream>>>(
      gate, wslot, out, x1, BT_, D_, FF_, FF_, FF_, D_, 0, 0, 0, 0, 0, 0, 0);
}

// Round 4
// 1475.586 us; speedup vs baseline: 1.0221x; 1.0221x over previous
//
#include <hip/hip_runtime.h>
#include <cstdint>

#define D_  2048
#define H_  16
#define HD_ 128
#define FF_ 8192
#define T_  2048
#define B_  2
#define BT_ (B_*T_)
#define NP_ (B_*H_)        // 32 (b,h) pairs
#define CH_ 8              // pairs per attention chunk
#define NCH_ (NP_/CH_)     // 4 chunks

typedef __attribute__((ext_vector_type(8))) _Float16 half8;
typedef __attribute__((ext_vector_type(4))) float   floatx4;

// async global->LDS, 16B per lane; LDS dest = wave-uniform base + lane*16
__device__ __forceinline__ void gl_lds16(const void* g, void* l) {
  __builtin_amdgcn_global_load_lds(
      (const __attribute__((address_space(1))) void*)(uintptr_t)g,
      (__attribute__((address_space(3))) void*)(uintptr_t)l,
      16, 0, 0);
}

// ---------------- weight convert + transpose: W[K][N] f32 -> Wt[N][K] f16 ----
__global__ void wconv_kernel(const float* __restrict__ W, _Float16* __restrict__ Wt,
                             int K, int N) {
  __shared__ float tile[32][33];
  int n0 = blockIdx.x * 32, k0 = blockIdx.y * 32;
  int tx = threadIdx.x, ty = threadIdx.y;   // 32 x 8
#pragma unroll
  for (int r = 0; r < 32; r += 8)
    tile[ty + r][tx] = W[(size_t)(k0 + ty + r) * N + n0 + tx];
  __syncthreads();
#pragma unroll
  for (int r = 0; r < 32; r += 8)
    Wt[(size_t)(n0 + ty + r) * K + k0 + tx] = (_Float16)tile[tx][ty + r];
}

// ---------------- rmsnorm: fp32 row -> fp16 row --------------------------------
__global__ void rmsnorm_kernel(const float* __restrict__ x, const float* __restrict__ g,
                               _Float16* __restrict__ out) {
  int row = blockIdx.x, tid = threadIdx.x;
  const float4* xr = (const float4*)(x + (size_t)row * D_);
  float4 v1 = xr[tid], v2 = xr[tid + 256];
  float ss = v1.x*v1.x + v1.y*v1.y + v1.z*v1.z + v1.w*v1.w
           + v2.x*v2.x + v2.y*v2.y + v2.z*v2.z + v2.w*v2.w;
  __shared__ float red[256];
  red[tid] = ss; __syncthreads();
  for (int s = 128; s > 0; s >>= 1) { if (tid < s) red[tid] += red[tid + s]; __syncthreads(); }
  float rs = rsqrtf(red[0] * (1.0f / D_) + 1e-6f);
  float4 ga = ((const float4*)g)[tid], gb = ((const float4*)g)[tid + 256];
  _Float16* orow = out + (size_t)row * D_;
  _Float16 t[4] __attribute__((aligned(8)));
  t[0] = (_Float16)(v1.x * rs * ga.x);
  t[1] = (_Float16)(v1.y * rs * ga.y);
  t[2] = (_Float16)(v1.z * rs * ga.z);
  t[3] = (_Float16)(v1.w * rs * ga.w);
  *(uint2*)(orow + tid * 4) = *(const uint2*)t;
  t[0] = (_Float16)(v2.x * rs * gb.x);
  t[1] = (_Float16)(v2.y * rs * gb.y);
  t[2] = (_Float16)(v2.z * rs * gb.z);
  t[3] = (_Float16)(v2.w * rs * gb.w);
  *(uint2*)(orow + (tid + 256) * 4) = *(const uint2*)t;
}

// ---------------- generic MFMA GEMM, C = A @ Bt^T ------------------------------
// A: M x K (lda), Bt: N x K (ldb), C: M x N (ldc).  128x128 tile, 4 waves.
// Staging: global_load_lds dwordx4 into unpadded [row][32] fp16 LDS tiles.
// CMODE: 0 none, 1 causal tile-skip (scores), 2 causal K-limit (PV).
// ADDRES: 1 -> C fp32 = acc + Res;  0 -> C fp16 = acc.
// Batch: p = pair0 + blockIdx.z; b=p>>4, h=p&15.
//   A offset: (LOCALS&1) ? blockIdx.z*sAd : b*sAd + h*sAm
//   B offset:                               b*sBd + h*sBm
//   C offset: (LOCALS&2) ? blockIdx.z*sCd : b*sCd + h*sCm
template<int CMODE, int ADDRES, int LOCALS>
__global__ __launch_bounds__(256, 3) void gemm_bt(
    const _Float16* __restrict__ A, const _Float16* __restrict__ Bt,
    void* __restrict__ Cv, const float* __restrict__ Res,
    int M, int N, int K, int lda, int ldb, int ldc, int pair0,
    long long sAd, long long sAm, long long sBd, long long sBm,
    long long sCd, long long sCm)
{
  int zl = blockIdx.z;
  int p = pair0 + zl;
  long long aoff = (LOCALS & 1) ? (long long)zl * sAd
                                : (long long)(p >> 4) * sAd + (long long)(p & 15) * sAm;
  long long boff = (long long)(p >> 4) * sBd + (long long)(p & 15) * sBm;
  long long coff = (LOCALS & 2) ? (long long)zl * sCd
                                : (long long)(p >> 4) * sCd + (long long)(p & 15) * sCm;
  const _Float16* Ab = A + (size_t)aoff;
  const _Float16* Bb = Bt + (size_t)boff;
  int m0 = blockIdx.y * 128, n0 = blockIdx.x * 128;
  if (CMODE == 1 && n0 > m0 + 127) return;
  int kmax = K;
  if (CMODE == 2) kmax = min(K, m0 + 128);

  __shared__ __align__(16) _Float16 As[128 * 32];
  __shared__ __align__(16) _Float16 Bs[128 * 32];

  int tid = threadIdx.x;
  int lane = tid & 63;
  int w = tid >> 6;                 // wave 0..3
  int wm = ((tid >> 7) & 1) * 64;   // wave row
  int wn = ((tid >> 6) & 1) * 64;   // wave col
  int l15 = lane & 15, q4 = lane >> 4;

  // staging addresses: wave w stages rows [w*32, w*32+32) of both tiles,
  // two 16-row instructions each. lane covers (row = base + lane/4, col = (lane&3)*8).
  int arow = w * 32;
  int lrow = lane >> 2, lcol = (lane & 3) * 8;
  const _Float16* Ag = Ab + (size_t)(m0 + arow + lrow) * lda + lcol;
  const _Float16* Bg = Bb + (size_t)(n0 + arow + lrow) * ldb + lcol;
  const _Float16* Ag2 = Ag + (size_t)16 * lda;
  const _Float16* Bg2 = Bg + (size_t)16 * ldb;
  _Float16* lA  = &As[arow * 32];
  _Float16* lA2 = &As[(arow + 16) * 32];
  _Float16* lB  = &Bs[arow * 32];
  _Float16* lB2 = &Bs[(arow + 16) * 32];

  floatx4 acc[4][4];
#pragma unroll
  for (int i = 0; i < 4; i++)
#pragma unroll
    for (int j = 0; j < 4; j++)
#pragma unroll
      for (int r = 0; r < 4; r++) acc[i][j][r] = 0.0f;

  for (int k0 = 0; k0 < kmax; k0 += 32) {
    gl_lds16(Ag + k0, lA);
    gl_lds16(Ag2 + k0, lA2);
    gl_lds16(Bg + k0, lB);
    gl_lds16(Bg2 + k0, lB2);
    __syncthreads();
    half8 af[4], bfr[4];
#pragma unroll
    for (int i = 0; i < 4; i++)
      af[i] = *(const half8*)(&As[(wm + i * 16 + l15) * 32 + q4 * 8]);
#pragma unroll
    for (int j = 0; j < 4; j++)
      bfr[j] = *(const half8*)(&Bs[(wn + j * 16 + l15) * 32 + q4 * 8]);
#pragma unroll
    for (int i = 0; i < 4; i++)
#pragma unroll
      for (int j = 0; j < 4; j++)
        acc[i][j] = __builtin_amdgcn_mfma_f32_16x16x32_f16(af[i], bfr[j], acc[i][j], 0, 0, 0);
    __syncthreads();
  }

#pragma unroll
  for (int i = 0; i < 4; i++) {
#pragma unroll
    for (int j = 0; j < 4; j++) {
#pragma unroll
      for (int r = 0; r < 4; r++) {
        int row = m0 + wm + i * 16 + q4 * 4 + r;
        int col = n0 + wn + j * 16 + l15;
        size_t o = (size_t)(coff + (long long)row * ldc + col);
        if (ADDRES) ((float*)Cv)[o] = acc[i][j][r] + Res[o];
        else        ((_Float16*)Cv)[o] = (_Float16)acc[i][j][r];
      }
    }
  }
}

// ---------------- RoPE on q and k (in place) ------------------------------------
__global__ void rope_kernel(_Float16* __restrict__ q, _Float16* __restrict__ k,
                            const void* __restrict__ pos) {
  int gid = blockIdx.x * 256 + threadIdx.x;   // BT_*H_*64 threads
  int d = gid & 63;
  int h = (gid >> 6) & 15;
  int bt = gid >> 10;
  const int* pi = (const int*)pos;
  // detect int64 vs int32 layout of position_ids (values are arange 0..BT-1)
  long long p = (pi[1] == 0 && pi[2] == 1) ? ((const long long*)pos)[bt]
                                           : (long long)pi[bt];
  float inv = exp2f((float)d * -0.2076205059304601f);  // 10000^(-d/64)
  float ang = (float)p * inv;
  float s, c;
  sincosf(ang, &s, &c);   // accurate path; signature is (x, &sin, &cos)
  size_t base = (size_t)bt * D_ + (size_t)h * HD_ + d;
  float x1 = (float)q[base], x2 = (float)q[base + 64];
  q[base]      = (_Float16)(x1 * c - x2 * s);
  q[base + 64] = (_Float16)(x2 * c + x1 * s);
  x1 = (float)k[base]; x2 = (float)k[base + 64];
  k[base]      = (_Float16)(x1 * c - x2 * s);
  k[base + 64] = (_Float16)(x2 * c + x1 * s);
}

// ---------------- v[b][t][h*HD+d] -> vt[(b*H+h)][d][t] --------------------------
__global__ void vtrans_kernel(const _Float16* __restrict__ v, _Float16* __restrict__ vt) {
  __shared__ _Float16 tile[32][33];
  int t0 = blockIdx.x * 32, d0 = blockIdx.y * 32, bh = blockIdx.z;
  int b = bh >> 4, h = bh & 15;
  int tx = threadIdx.x, ty = threadIdx.y;   // 32 x 8
  const _Float16* vb = v + (size_t)b * T_ * D_ + (size_t)h * HD_;
#pragma unroll
  for (int r = 0; r < 32; r += 8)
    tile[ty + r][tx] = vb[(size_t)(t0 + ty + r) * D_ + d0 + tx];
  __syncthreads();
  _Float16* vo = vt + ((size_t)bh * HD_ + d0) * T_ + t0;
#pragma unroll
  for (int r = 0; r < 32; r += 8)
    vo[(size_t)(ty + r) * T_ + tx] = tile[tx][ty + r];
}

// ---------------- causal softmax over one row of scores (in place) --------------
__global__ void softmax_kernel(_Float16* __restrict__ probs) {
  long long rowid = blockIdx.x;
  int i = (int)(rowid & (T_ - 1));
  _Float16* row = probs + (size_t)rowid * T_;
  int tid = threadIdx.x;
  int j0 = tid * 8;
  uint4 raw = *(const uint4*)(row + j0);
  const _Float16* ph = (const _Float16*)&raw;
  const float scale = 0.08838834764831845f;     // 1/sqrt(128)
  float vals[8];
  float mx = -1e30f;
#pragma unroll
  for (int l = 0; l < 8; l++) {
    float v = (j0 + l <= i) ? (float)ph[l] * scale : -1e30f;
    vals[l] = v; mx = fmaxf(mx, v);
  }
  __shared__ float red[256];
  red[tid] = mx; __syncthreads();
  for (int s = 128; s > 0; s >>= 1) { if (tid < s) red[tid] = fmaxf(red[tid], red[tid + s]); __syncthreads(); }
  float M = red[0]; __syncthreads();
  float se = 0.f;
#pragma unroll
  for (int l = 0; l < 8; l++) { float e = __expf(vals[l] - M); vals[l] = e; se += e; }
  red[tid] = se; __syncthreads();
  for (int s = 128; s > 0; s >>= 1) { if (tid < s) red[tid] += red[tid + s]; __syncthreads(); }
  float inv = 1.0f / red[0];
  _Float16 t[8] __attribute__((aligned(16)));
#pragma unroll
  for (int l = 0; l < 8; l++) t[l] = (j0 + l <= i) ? (_Float16)(vals[l] * inv) : (_Float16)0.f;
  *(uint4*)(row + j0) = *(const uint4*)t;
}

// ---------------- hu = silu(gate) * up  (written over gate) ---------------------
__global__ void silumul_kernel(_Float16* __restrict__ gate, const _Float16* __restrict__ up) {
  size_t idx = ((size_t)blockIdx.x * 256 + threadIdx.x) * 8;
  uint4 gr = *(const uint4*)(gate + idx);
  uint4 ur = *(const uint4*)(up + idx);
  const _Float16* gh = (const _Float16*)&gr;
  const _Float16* uh = (const _Float16*)&ur;
  _Float16 t[8] __attribute__((aligned(16)));
#pragma unroll
  for (int l = 0; l < 8; l++) {
    float x = (float)gh[l];
    float s = x / (1.0f + __expf(-x));
    t[l] = (_Float16)(s * (float)uh[l]);
  }
  *(uint4*)(gate + idx) = *(const uint4*)t;
}

// ================================================================================
extern "C" void kernel_launch(void* const* d_in, const int* in_sizes, int n_in,
                              void* d_out, int out_size, void* d_ws, size_t ws_size,
                              hipStream_t stream) {
  (void)in_sizes; (void)n_in; (void)out_size;
  const float* x   = (const float*)d_in[0];
  const void*  pos = d_in[1];
  const float* W[7] = { (const float*)d_in[2], (const float*)d_in[3],
                        (const float*)d_in[4], (const float*)d_in[5],
                        (const float*)d_in[6], (const float*)d_in[7],
                        (const float*)d_in[8] };              // q k v o g u d
  const float* g1  = (const float*)d_in[9];
  const float* g2  = (const float*)d_in[10];
  float* out = (float*)d_out;

  // weight dims: {K, N} per weight
  const int wk[7] = { D_, D_, D_, D_, D_, D_, FF_ };
  const int wn[7] = { D_, D_, D_, D_, FF_, FF_, D_ };

  char* p = (char*)d_ws;
  auto carve = [&](size_t bytes) { char* r = p; p += (bytes + 255) & ~(size_t)255; return r; };

  _Float16* probs = (_Float16*)carve((size_t)CH_ * T_ * T_ * 2);   // 64 MB; later: gate
  // flat mode: all 7 weights resident (128 MB). rotating: one 32 MB slot.
  const size_t FLAT_NEED = (size_t)336 * 1024 * 1024;
  bool flat = ws_size >= FLAT_NEED;
  _Float16* w16[7];
  if (flat) {
    for (int i = 0; i < 7; i++) w16[i] = (_Float16*)carve((size_t)wk[i] * wn[i] * 2);
  } else {
    _Float16* wslot = (_Float16*)carve((size_t)D_ * FF_ * 2);
    for (int i = 0; i < 7; i++) w16[i] = wslot;
  }
  _Float16* qb = (_Float16*)carve((size_t)BT_ * D_ * 2);  // later: hb
  _Float16* xn = (_Float16*)carve((size_t)BT_ * D_ * 2);  // later: ob, part of up
  _Float16* kb = (_Float16*)carve((size_t)BT_ * D_ * 2);
  _Float16* vb = (_Float16*)carve((size_t)BT_ * D_ * 2);
  _Float16* vt = (_Float16*)carve((size_t)BT_ * D_ * 2);
  float*    x1 = (float*)   carve((size_t)BT_ * D_ * 4);
  _Float16* gate = probs;
  _Float16* up   = xn;      // spans xn|kb|vb|vt (all dead)
  _Float16* ob   = xn;
  _Float16* hb   = qb;

  dim3 b328(32, 8);
  auto conv = [&](int i) {
    wconv_kernel<<<dim3(wn[i] / 32, wk[i] / 32), b328, 0, stream>>>(W[i], w16[i], wk[i], wn[i]);
  };
  if (flat) for (int i = 0; i < 7; i++) conv(i);

  // xn = rmsnorm(x, g1)
  rmsnorm_kernel<<<BT_, 256, 0, stream>>>(x, g1, xn);

  // q, k, v projections
  if (!flat) conv(0);
  gemm_bt<0, 0, 0><<<dim3(D_ / 128, BT_ / 128, 1), 256, 0, stream>>>(
      xn, w16[0], qb, nullptr, BT_, D_, D_, D_, D_, D_, 0, 0, 0, 0, 0, 0, 0);
  if (!flat) conv(1);
  gemm_bt<0, 0, 0><<<dim3(D_ / 128, BT_ / 128, 1), 256, 0, stream>>>(
      xn, w16[1], kb, nullptr, BT_, D_, D_, D_, D_, D_, 0, 0, 0, 0, 0, 0, 0);
  if (!flat) conv(2);
  gemm_bt<0, 0, 0><<<dim3(D_ / 128, BT_ / 128, 1), 256, 0, stream>>>(
      xn, w16[2], vb, nullptr, BT_, D_, D_, D_, D_, D_, 0, 0, 0, 0, 0, 0, 0);

  // rope(q, k)
  rope_kernel<<<(BT_ * H_ * 64) / 256, 256, 0, stream>>>(qb, kb, pos);

  // v transpose per head: vt[(b*H+h)][d][t]
  vtrans_kernel<<<dim3(T_ / 32, HD_ / 32, B_ * H_), b328, 0, stream>>>(vb, vt);

  // attention in chunks of CH_ (b,h) pairs
  for (int c = 0; c < NCH_; c++) {
    gemm_bt<1, 0, 2><<<dim3(T_ / 128, T_ / 128, CH_), 256, 0, stream>>>(
        qb, kb, probs, nullptr, T_, T_, HD_, D_, D_, T_, c * CH_,
        (long long)T_ * D_, HD_, (long long)T_ * D_, HD_,
        (long long)T_ * T_, 0);
    softmax_kernel<<<CH_ * T_, 256, 0, stream>>>(probs);
    gemm_bt<2, 0, 1><<<dim3(1, T_ / 128, CH_), 256, 0, stream>>>(
        probs, vt, ob, nullptr, T_, HD_, T_, T_, T_, D_, c * CH_,
        (long long)T_ * T_, 0,
        16LL * HD_ * T_, (long long)HD_ * T_,
        (long long)T_ * D_, HD_);
  }

  // x1 = x + o @ Wo
  if (!flat) conv(3);
  gemm_bt<0, 1, 0><<<dim3(D_ / 128, BT_ / 128, 1), 256, 0, stream>>>(
      ob, w16[3], x1, x, BT_, D_, D_, D_, D_, D_, 0, 0, 0, 0, 0, 0, 0);

  // h = rmsnorm(x1, g2)
  rmsnorm_kernel<<<BT_, 256, 0, stream>>>(x1, g2, hb);

  // gate = h @ Wg ; up = h @ Wu
  if (!flat) conv(4);
  gemm_bt<0, 0, 0><<<dim3(FF_ / 128, BT_ / 128, 1), 256, 0, stream>>>(
      hb, w16[4], gate, nullptr, BT_, FF_, D_, D_, D_, FF_, 0, 0, 0, 0, 0, 0, 0);
  if (!flat) conv(5);
  gemm_bt<0, 0, 0><<<dim3(FF_ / 128, BT_ / 128, 1), 256, 0, stream>>>(
      hb, w16[5], up, nullptr, BT_, FF_, D_, D_, D_, FF_, 0, 0, 0, 0, 0, 0, 0);

  // hu = silu(gate) * up  (in gate)
  silumul_kernel<<<(BT_ * FF_ / 8) / 256, 256, 0, stream>>>(gate, up);

  // out = x1 + hu @ Wd
  if (!flat) conv(6);
  gemm_bt<0, 1, 0><<<dim3(D_ / 128, BT_ / 128, 1), 256, 0, stream>>>(
      gate, w16[6], out, x1, BT_, D_, FF_, FF_, FF_, D_, 0, 0, 0, 0, 0, 0, 0);
}